// Round 7
// baseline (291.114 us; speedup 1.0000x reference)
//
#include <hip/hip_runtime.h>

typedef float f4 __attribute__((ext_vector_type(4)));
typedef __attribute__((ext_vector_type(8))) short bf16x8;
typedef __attribute__((ext_vector_type(4))) float f32x4;
typedef __attribute__((ext_vector_type(2))) int i32x2;
typedef __attribute__((ext_vector_type(4))) int i32x4;

#define T_SEQ 2048
#define NFEAT 512
#define NHEAD 8
#define DK    64
#define BATCH 4

using gptr_t = const __attribute__((address_space(1))) void*;
using lptr_t = __attribute__((address_space(3))) void*;

#define LOG2E_8 0.18033688011f   // 0.125 * log2(e)

// ---------------- failure ledger (do not retry without new evidence) -----------
// 1. v_cvt_pk_bf16_f32 inline asm for P-pack: FAILED correctness (absmax 0.227).
// 2. __launch_bounds__(512,8) 8-wave attn: VGPR cap 32 -> scratch spill,
//    WRITE_SIZE 24->149MB, attn 63.5->100.7us. Occupancy must come from LDS.
// 3. t-tile 64 attn (5 blocks/CU): staging per iter unchanged, compute halved ->
//    staging-bound, attn 63.5->68.9us.
// 4. combine->gemm_out fusion: neutral. Kept (less traffic, fewer dispatches).
// 5. swapped-QK + kappa (Ps LDS deleted, -29% LDS traffic): NEUTRAL on time
//    (65us). Together with #3/#4: VALU cut, LDS cut, occupancy moves all
//    neutral => phases are barrier-serialized; pipe busies sum to the wall.
// => this round: delete LDS staging + ALL barriers; read KP/Vt/cb fragments
//    directly from L2-resident global (KV = 2MB per XCD, L2 4MB). Waves
//    free-run -> cross-wave pipe overlap. (Guide lesson #7 precedent.)

static __device__ __forceinline__ short f2bf(float f) {
    unsigned u = __builtin_bit_cast(unsigned, f);
    u += 0x7fff + ((u >> 16) & 1);          // round-to-nearest-even
    return (short)(u >> 16);
}
static __device__ __forceinline__ float b2f(short s) {
    unsigned u = ((unsigned)(unsigned short)s) << 16;
    return __builtin_bit_cast(float, u);
}
// cheap-round pack (P values; same numerics as previous rounds)
static __device__ __forceinline__ int pkbf(float a, float b) {
    unsigned ua = __builtin_bit_cast(unsigned, a) + 0x8000u;
    unsigned ub = __builtin_bit_cast(unsigned, b) + 0x8000u;
    return (int)((ua >> 16) | (ub & 0xFFFF0000u));
}
// RNE pack (epilogue O partials)
static __device__ __forceinline__ int pkbf_rne(float a, float b) {
    unsigned ua = __builtin_bit_cast(unsigned, a); ua += 0x7fff + ((ua >> 16) & 1);
    unsigned ub = __builtin_bit_cast(unsigned, b); ub += 0x7fff + ((ub >> 16) & 1);
    return (int)((ua >> 16) | (ub & 0xFFFF0000u));
}

// ---------------- fused fp32->bf16 conversion + weight/bias packing -------------
__global__ __launch_bounds__(256) void cvt_kernel(
    const float* __restrict__ x, const float* __restrict__ pos,
    const float* __restrict__ Wq, const float* __restrict__ Wk, const float* __restrict__ Wv,
    const float* __restrict__ Wpos, const float* __restrict__ Wout,
    const float* __restrict__ bq, const float* __restrict__ bk, const float* __restrict__ bv,
    short* __restrict__ xb, short* __restrict__ posb, short* __restrict__ wqkv,
    short* __restrict__ wpb, short* __restrict__ wob, float* __restrict__ bqkv)
{
    const int blk = blockIdx.x;
    const float* src; short* dst; int off;
    if      (blk < 2048) { src = x;    dst = xb;          off = blk * 2048; }
    else if (blk < 2560) { src = pos;  dst = posb;        off = (blk - 2048) * 2048; }
    else if (blk < 2688) { src = Wq;   dst = wqkv;        off = (blk - 2560) * 2048; }
    else if (blk < 2816) { src = Wk;   dst = wqkv + 262144; off = (blk - 2688) * 2048; }
    else if (blk < 2944) { src = Wv;   dst = wqkv + 524288; off = (blk - 2816) * 2048; }
    else if (blk < 3072) { src = Wpos; dst = wpb;         off = (blk - 2944) * 2048; }
    else if (blk < 3200) { src = Wout; dst = wob;         off = (blk - 3072) * 2048; }
    else {
        int t = threadIdx.x;
        bqkv[t]        = bq[t];        bqkv[256 + t]  = bq[256 + t];
        bqkv[512 + t]  = bk[t];        bqkv[768 + t]  = bk[256 + t];
        bqkv[1024 + t] = bv[t];        bqkv[1280 + t] = bv[256 + t];
        return;
    }
    int i = off + threadIdx.x * 8;
    f4 a = *(const f4*)(src + i);
    f4 b = *(const f4*)(src + i + 4);
    bf16x8 o;
#pragma unroll
    for (int j = 0; j < 4; ++j) { o[j] = f2bf(a[j]); o[4 + j] = f2bf(b[j]); }
    *(bf16x8*)(dst + i) = o;
}

// ---------------- bf16 MFMA GEMM tile: C[128,128] = A@B^T + bias ---------------
template<int OUT_BF16>
static __device__ __forceinline__ void gemm_tile(
    short* As, short* Bs,
    const short* __restrict__ A, const short* __restrict__ B,
    const float* __restrict__ bias, void* __restrict__ Cv,
    int N, int K, int row0, int col0)
{
    const int tid = threadIdx.x, lane = tid & 63, wave = tid >> 6;
    const int col = lane & 15, quad = lane >> 4;
    const int wm = (wave >> 1) * 64, wn = (wave & 1) * 64;
    const int rl = lane & 15;

    const short* Abase = A + (size_t)(row0 + wave * 32 + rl) * K + (lane >> 4) * 8;
    const short* Bbase = B + (size_t)(col0 + wave * 32 + rl) * K + (lane >> 4) * 8;

    f32x4 acc[4][4];
#pragma unroll
    for (int i = 0; i < 4; ++i)
#pragma unroll
        for (int j = 0; j < 4; ++j) acc[i][j] = (f32x4){0.f, 0.f, 0.f, 0.f};

    for (int k0 = 0; k0 < K; k0 += 64) {
        __syncthreads();
#pragma unroll
        for (int c = 0; c < 2; ++c)
#pragma unroll
            for (int hf = 0; hf < 2; ++hf) {
                __builtin_amdgcn_global_load_lds((gptr_t)(Abase + (size_t)(16 * c) * K + k0 + hf * 32),
                                                 (lptr_t)(As + wave * 2048 + c * 1024 + hf * 512), 16, 0, 0);
                __builtin_amdgcn_global_load_lds((gptr_t)(Bbase + (size_t)(16 * c) * K + k0 + hf * 32),
                                                 (lptr_t)(Bs + wave * 2048 + c * 1024 + hf * 512), 16, 0, 0);
            }
        __syncthreads();
#pragma unroll
        for (int kt = 0; kt < 2; ++kt) {
            bf16x8 af[4], bfr[4];
#pragma unroll
            for (int mt = 0; mt < 4; ++mt)
                af[mt] = *(const bf16x8*)&As[((wm >> 4) + mt) * 1024 + (kt * 4 + quad) * 128 + col * 8];
#pragma unroll
            for (int nt = 0; nt < 4; ++nt)
                bfr[nt] = *(const bf16x8*)&Bs[((wn >> 4) + nt) * 1024 + (kt * 4 + quad) * 128 + col * 8];
#pragma unroll
            for (int mt = 0; mt < 4; ++mt)
#pragma unroll
                for (int nt = 0; nt < 4; ++nt)
                    acc[mt][nt] = __builtin_amdgcn_mfma_f32_16x16x32_bf16(af[mt], bfr[nt], acc[mt][nt], 0, 0, 0);
        }
    }

    float bv4[4];
#pragma unroll
    for (int nt = 0; nt < 4; ++nt)
        bv4[nt] = bias ? bias[col0 + wn + nt * 16 + col] : 0.f;
#pragma unroll
    for (int mt = 0; mt < 4; ++mt)
#pragma unroll
        for (int reg = 0; reg < 4; ++reg) {
            int r = row0 + wm + mt * 16 + quad * 4 + reg;
#pragma unroll
            for (int nt = 0; nt < 4; ++nt) {
                int c = col0 + wn + nt * 16 + col;
                float v = acc[mt][nt][reg] + bv4[nt];
                if (OUT_BF16) ((short*)Cv)[(size_t)r * N + c] = f2bf(v);
                else          ((float*)Cv)[(size_t)r * N + c] = v;
            }
        }
}

// QKV (768 tiles, XCD-swizzled) + pos (64 tiles) in one dispatch
__global__ __launch_bounds__(256) void gemm_qkv_pos(
    const short* __restrict__ xb, const short* __restrict__ wqkv,
    const float* __restrict__ bqkv, short* __restrict__ QKV,
    const short* __restrict__ posb, const short* __restrict__ wpb,
    short* __restrict__ Pm)
{
    __shared__ short As[8192], Bs[8192];
    const int bid = blockIdx.x;
    if (bid < 768) {
        const int xcd = bid & 7, s = bid >> 3;
        const int row = xcd * 8 + (s & 7), colt = s >> 3;   // row 0..63, colt 0..11
        gemm_tile<1>(As, Bs, xb, wqkv, bqkv, QKV, 1536, 512, row * 128, colt * 128);
    } else {
        const int t = bid - 768;
        gemm_tile<1>(As, Bs, posb, wpb, nullptr, Pm, 512, 512, (t / 4) * 128, (t % 4) * 128);
    }
}

// ---------------- gemm_out with combine FUSED into A-staging -------------------
__global__ __launch_bounds__(256) void gemm_out_kernel(
    const short* __restrict__ Op, const float* __restrict__ Lb,
    const short* __restrict__ B, const float* __restrict__ bias,
    float* __restrict__ C)
{
    __shared__ short As[8192], Bs[8192];
    const int bid = blockIdx.x;
    const int xcd = bid & 7, s = bid >> 3;
    const int row0 = (xcd * 8 + (s & 7)) * 128, col0 = (s >> 3) * 128;
    const int N = 512, K = 512;

    const int tid = threadIdx.x, lane = tid & 63, wave = tid >> 6;
    const int col = lane & 15, quad = lane >> 4;
    const int wm = (wave >> 1) * 64, wn = (wave & 1) * 64;
    const int rl = lane & 15;

    const short* Bbase = B + (size_t)(col0 + wave * 32 + rl) * K + quad * 8;
    const int rA0 = row0 + wave * 32 + rl;   // c=0 staging row; c=1 is +16

    f32x4 acc[4][4];
#pragma unroll
    for (int i = 0; i < 4; ++i)
#pragma unroll
        for (int j = 0; j < 4; ++j) acc[i][j] = (f32x4){0.f, 0.f, 0.f, 0.f};

    for (int k0 = 0; k0 < K; k0 += 64) {
        const int h = k0 >> 6;
        __syncthreads();
        // B staging first (stays in flight under the A combine)
#pragma unroll
        for (int c = 0; c < 2; ++c)
#pragma unroll
            for (int hf = 0; hf < 2; ++hf)
                __builtin_amdgcn_global_load_lds((gptr_t)(Bbase + (size_t)(16 * c) * K + k0 + hf * 32),
                                                 (lptr_t)(Bs + wave * 2048 + c * 1024 + hf * 512), 16, 0, 0);
        // A staging: combine two unnormalized halves, normalize, ds_write
#pragma unroll
        for (int c = 0; c < 2; ++c) {
            const int r  = rA0 + c * 16;
            const int t  = r & 2047;
            const int bh = (r >> 11) * 8 + h;
            const float l = Lb[bh * T_SEQ + t] + Lb[65536 + bh * T_SEQ + t];
            const float inv = 1.f / l;
#pragma unroll
            for (int hf = 0; hf < 2; ++hf) {
                const short* src = Op + (size_t)r * NFEAT + k0 + hf * 32 + quad * 8;
                bf16x8 o1 = *(const bf16x8*)src;
                bf16x8 o2 = *(const bf16x8*)(src + 4194304);
                bf16x8 oc;
#pragma unroll
                for (int j = 0; j < 8; ++j) oc[j] = f2bf((b2f(o1[j]) + b2f(o2[j])) * inv);
                *(bf16x8*)&As[wave * 2048 + c * 1024 + hf * 512 + lane * 8] = oc;
            }
        }
        __syncthreads();
#pragma unroll
        for (int kt = 0; kt < 2; ++kt) {
            bf16x8 af[4], bfr[4];
#pragma unroll
            for (int mt = 0; mt < 4; ++mt)
                af[mt] = *(const bf16x8*)&As[((wm >> 4) + mt) * 1024 + (kt * 4 + quad) * 128 + col * 8];
#pragma unroll
            for (int nt = 0; nt < 4; ++nt)
                bfr[nt] = *(const bf16x8*)&Bs[((wn >> 4) + nt) * 1024 + (kt * 4 + quad) * 128 + col * 8];
#pragma unroll
            for (int mt = 0; mt < 4; ++mt)
#pragma unroll
                for (int nt = 0; nt < 4; ++nt)
                    acc[mt][nt] = __builtin_amdgcn_mfma_f32_16x16x32_bf16(af[mt], bfr[nt], acc[mt][nt], 0, 0, 0);
        }
    }

    float bv4[4];
#pragma unroll
    for (int nt = 0; nt < 4; ++nt)
        bv4[nt] = bias[col0 + wn + nt * 16 + col];
#pragma unroll
    for (int mt = 0; mt < 4; ++mt)
#pragma unroll
        for (int reg = 0; reg < 4; ++reg) {
            int r = row0 + wm + mt * 16 + quad * 4 + reg;
#pragma unroll
            for (int nt = 0; nt < 4; ++nt) {
                int c = col0 + wn + nt * 16 + col;
                C[(size_t)r * N + c] = acc[mt][nt][reg] + bv4[nt];
            }
        }
}

// ---------------- fused: KP = K+P, cb = (log2e/8)*(u.k+vb.p), Vt transpose -----
__global__ __launch_bounds__(256) void kvprep_kernel(
    const short* __restrict__ qkv, const short* __restrict__ pm,
    const float* __restrict__ u, const float* __restrict__ vb,
    short* __restrict__ kp, short* __restrict__ vt, float* __restrict__ cb)
{
    __shared__ short tile[64][72];
    const int tid = threadIdx.x, lr = tid >> 2, lc = (tid & 3) * 16;
    const int bh = blockIdx.y, b = bh >> 3, h = bh & 7, s0 = blockIdx.x * 64;

    const short* kptr = qkv + (size_t)(b * T_SEQ + s0 + lr) * 1536 + 512 + h * DK + lc;
    const short* pptr = pm + (size_t)(s0 + lr) * NFEAT + h * DK + lc;
    const short* vptr = qkv + (size_t)(b * T_SEQ + s0 + lr) * 1536 + 1024 + h * DK + lc;
    bf16x8 k0_ = *(const bf16x8*)kptr,       k1_ = *(const bf16x8*)(kptr + 8);
    bf16x8 p0_ = *(const bf16x8*)pptr,       p1_ = *(const bf16x8*)(pptr + 8);
    bf16x8 v0_ = *(const bf16x8*)vptr,       v1_ = *(const bf16x8*)(vptr + 8);

    float c = 0.f;
    bf16x8 o0, o1;
#pragma unroll
    for (int j = 0; j < 8; ++j) {
        float kf = b2f(k0_[j]), pf = b2f(p0_[j]);
        o0[j] = f2bf(kf + pf);
        c += u[h * DK + lc + j] * kf + vb[h * DK + lc + j] * pf;
        float kf1 = b2f(k1_[j]), pf1 = b2f(p1_[j]);
        o1[j] = f2bf(kf1 + pf1);
        c += u[h * DK + lc + 8 + j] * kf1 + vb[h * DK + lc + 8 + j] * pf1;
    }
    short* kpd = kp + ((size_t)bh * T_SEQ + s0 + lr) * DK + lc;
    *(bf16x8*)kpd       = o0;
    *(bf16x8*)(kpd + 8) = o1;
    c += __shfl_xor(c, 1);
    c += __shfl_xor(c, 2);
    if ((tid & 3) == 0) cb[(size_t)bh * T_SEQ + s0 + lr] = LOG2E_8 * c;

    *(bf16x8*)&tile[lr][lc]     = v0_;
    *(bf16x8*)&tile[lr][lc + 8] = v1_;
    __syncthreads();
    short* dst = vt + (size_t)(bh * DK + lr) * T_SEQ + s0 + lc;
    bf16x8 t0_, t1_;
#pragma unroll
    for (int j = 0; j < 8; ++j) { t0_[j] = tile[lc + j][lr]; t1_[j] = tile[lc + 8 + j][lr]; }
    *(bf16x8*)dst       = t0_;
    *(bf16x8*)(dst + 8) = t1_;
}

// ---------------- flash attention: barrier-free, direct-from-L2 ----------------
// Grid 1024 (4 blocks/CU). Swapped-QK layout (round-6, proven) but ALL operand
// fragments read directly from L2-resident global (KV = 2MB per XCD < 4MB L2):
// no LDS, no __syncthreads, no staging registers. Waves free-run so MFMA /
// VALU / L2 phases of different waves overlap (the staged version's pipe
// busies summed to the wall -> phase-serialized; this removes the serializer).
// Address math = staged mapping with the LDS hop removed (kappa folded into
// per-nt immediate offsets {0,4,32,36}):
//   QK  a0/a1: kp[bh][base+it*64 + ntoff + ((col&12)<<1)+(col&3)][quad*8 (+32)]
//   cs  (f4):  cb[bh][base+it*64 + ntoff + quad*8 + 0..3]
//   PV  vb:    vt[bh][dt*16+col][base+it*64 + kt*32 + quad*8]
__global__ __launch_bounds__(256, 4) void attn_kernel(
    const short* __restrict__ qkv, const short* __restrict__ kp,
    const short* __restrict__ vt, const float* __restrict__ cb,
    short* __restrict__ Op, float* __restrict__ Lb)
{
    const int tid = threadIdx.x, lane = tid & 63, wave = tid >> 6;   // 4 waves
    const int col = lane & 15, quad = lane >> 4;
    const int idx = blockIdx.x;
    const int xcd = idx & 7, slot = idx >> 3;        // slot 0..127
    const int half = slot & 1;
    const int t0 = ((slot >> 1) & 15) * 128;
    const int bh = (slot >> 5) * 8 + xcd;            // 4 bh per XCD -> 2MB KV in L2
    const int base = half * 1024;                    // key range [base, base+1024)
    const int b = bh >> 3, h = bh & 7;

    // Q fragments (MFMA B-operand; unchanged)
    bf16x8 qa[2][2];
#pragma unroll
    for (int g = 0; g < 2; ++g) {
        const short* qb = qkv + (size_t)(b * T_SEQ + t0 + wave * 32 + g * 16 + col) * 1536 + h * DK + quad * 8;
        qa[g][0] = *(const bf16x8*)qb;
        qa[g][1] = *(const bf16x8*)(qb + 32);
    }

    // ones A-fragment (bf16 1.0) for the row-sum MFMA
    bf16x8 onesb;
#pragma unroll
    for (int j = 0; j < 8; ++j) onesb[j] = (short)0x3F80;

    // per-lane base pointers (kappa col-part folded in)
    const int colpart = ((col & 12) << 1) | (col & 3);
    const short* kpW = kp + (size_t)bh * T_SEQ * DK + (size_t)(base + colpart) * DK + quad * 8;
    const float* cbW = cb + (size_t)bh * T_SEQ + base + quad * 8;
    const short* vtW = vt + (size_t)bh * DK * T_SEQ + (size_t)col * T_SEQ + base + quad * 8;

    f32x4 Oacc[2][4];   // O^T: [g][dt], lane: d = dt*16+quad*4+reg, qrow = col+16g
    f32x4 Lacc[2];
#pragma unroll
    for (int g = 0; g < 2; ++g) {
        Lacc[g] = (f32x4){0.f, 0.f, 0.f, 0.f};
#pragma unroll
        for (int i = 0; i < 4; ++i) Oacc[g][i] = (f32x4){0.f, 0.f, 0.f, 0.f};
    }

    for (int it = 0; it < 16; ++it) {
        const int kq = it * 64 * DK;   // KP advance (elements)
        const int tq = it * 64;        // Vt / cb advance (elements)

        // QK swapped: S^T[slot][qrow]; KP fragments direct from L2
        f32x4 S[2][4];
#pragma unroll
        for (int g = 0; g < 2; ++g)
#pragma unroll
            for (int nt = 0; nt < 4; ++nt) S[g][nt] = (f32x4){0.f, 0.f, 0.f, 0.f};
#pragma unroll
        for (int nt = 0; nt < 4; ++nt) {
            const int ntoff = ((nt & 2) << 4) | ((nt & 1) << 2);   // {0,4,32,36}
            bf16x8 a0 = *(const bf16x8*)(kpW + kq + ntoff * DK);
            bf16x8 a1 = *(const bf16x8*)(kpW + kq + ntoff * DK + 32);
            S[0][nt] = __builtin_amdgcn_mfma_f32_16x16x32_bf16(a0, qa[0][0], S[0][nt], 0, 0, 0);
            S[1][nt] = __builtin_amdgcn_mfma_f32_16x16x32_bf16(a0, qa[1][0], S[1][nt], 0, 0, 0);
            S[0][nt] = __builtin_amdgcn_mfma_f32_16x16x32_bf16(a1, qa[0][1], S[0][nt], 0, 0, 0);
            S[1][nt] = __builtin_amdgcn_mfma_f32_16x16x32_bf16(a1, qa[1][1], S[1][nt], 0, 0, 0);
        }
        // softmax: exponent bias read direct (f4, contiguous in reg)
        int pk_[2][4][2];
#pragma unroll
        for (int nt = 0; nt < 4; ++nt) {
            const int ntoff = ((nt & 2) << 4) | ((nt & 1) << 2);
            const f4 cvn = *(const f4*)(cbW + tq + ntoff);
#pragma unroll
            for (int g = 0; g < 2; ++g) {
                float e0 = __builtin_amdgcn_exp2f(fmaf(S[g][nt][0], LOG2E_8, cvn[0]));
                float e1 = __builtin_amdgcn_exp2f(fmaf(S[g][nt][1], LOG2E_8, cvn[1]));
                float e2 = __builtin_amdgcn_exp2f(fmaf(S[g][nt][2], LOG2E_8, cvn[2]));
                float e3 = __builtin_amdgcn_exp2f(fmaf(S[g][nt][3], LOG2E_8, cvn[3]));
                pk_[g][nt][0] = pkbf(e0, e1);
                pk_[g][nt][1] = pkbf(e2, e3);
            }
        }
        // PV swapped: O^T += mfma(Vt-as-A, P-as-B); Vt fragments direct from L2
#pragma unroll
        for (int kt = 0; kt < 2; ++kt) {
            i32x4 w0 = (i32x4){pk_[0][2 * kt][0], pk_[0][2 * kt][1], pk_[0][2 * kt + 1][0], pk_[0][2 * kt + 1][1]};
            i32x4 w1 = (i32x4){pk_[1][2 * kt][0], pk_[1][2 * kt][1], pk_[1][2 * kt + 1][0], pk_[1][2 * kt + 1][1]};
            bf16x8 pf0 = __builtin_bit_cast(bf16x8, w0);
            bf16x8 pf1 = __builtin_bit_cast(bf16x8, w1);
            Lacc[0] = __builtin_amdgcn_mfma_f32_16x16x32_bf16(onesb, pf0, Lacc[0], 0, 0, 0);
            Lacc[1] = __builtin_amdgcn_mfma_f32_16x16x32_bf16(onesb, pf1, Lacc[1], 0, 0, 0);
#pragma unroll
            for (int dt = 0; dt < 4; ++dt) {
                bf16x8 vb = *(const bf16x8*)(vtW + tq + dt * 16 * T_SEQ + kt * 32);
                Oacc[0][dt] = __builtin_amdgcn_mfma_f32_16x16x32_bf16(vb, pf0, Oacc[0][dt], 0, 0, 0);
                Oacc[1][dt] = __builtin_amdgcn_mfma_f32_16x16x32_bf16(vb, pf1, Oacc[1][dt], 0, 0, 0);
            }
        }
    }
    // epilogue: O^T lane layout -> packed 8B stores; l from any Lacc row
    short* ophalf = Op + (size_t)half * 4194304;
    float* lhalf  = Lb + (size_t)half * 65536 + (size_t)bh * T_SEQ;
#pragma unroll
    for (int g = 0; g < 2; ++g) {
        const int t = t0 + wave * 32 + g * 16 + col;
        if (quad == 0) lhalf[t] = Lacc[g][0];
        short* op = ophalf + (size_t)(b * T_SEQ + t) * NFEAT + h * DK;
#pragma unroll
        for (int dt = 0; dt < 4; ++dt) {
            i32x2 w;
            w[0] = pkbf_rne(Oacc[g][dt][0], Oacc[g][dt][1]);
            w[1] = pkbf_rne(Oacc[g][dt][2], Oacc[g][dt][3]);
            *(i32x2*)(op + dt * 16 + quad * 4) = w;
        }
    }
}

extern "C" void kernel_launch(void* const* d_in, const int* in_sizes, int n_in,
                              void* d_out, int out_size, void* d_ws, size_t ws_size,
                              hipStream_t stream)
{
    const float* x    = (const float*)d_in[0];
    const float* pos  = (const float*)d_in[1];
    const float* Wq   = (const float*)d_in[2];
    const float* bq   = (const float*)d_in[3];
    const float* Wk   = (const float*)d_in[4];
    const float* bk   = (const float*)d_in[5];
    const float* Wv   = (const float*)d_in[6];
    const float* bv   = (const float*)d_in[7];
    const float* Wpos = (const float*)d_in[8];
    const float* Wout = (const float*)d_in[9];
    const float* bout = (const float*)d_in[10];
    const float* pbu  = (const float*)d_in[11];
    const float* pbv  = (const float*)d_in[12];
    float* out = (float*)d_out;

    short* xb   = (short*)d_ws;            // 4,194,304
    short* posb = xb   + 4194304;          // 1,048,576
    short* wqkv = posb + 1048576;          //   786,432
    short* wpb  = wqkv + 786432;           //   262,144
    short* wob  = wpb  + 262144;           //   262,144
    short* QKV  = wob  + 262144;           // 12,582,912  [8192][1536] (Q|K|V)
    short* Pm   = QKV  + 12582912;         // 1,048,576   [2048][512]
    short* KP   = Pm   + 1048576;          // 4,194,304   [bh][s][64]
    short* Vt   = KP   + 4194304;          // 4,194,304   [bh][d][t]
    short* AttO = Vt   + 4194304;          // 4,194,304   (unused after fusion)
    float* bqkv = (float*)(AttO + 4194304);
    float* Cb   = bqkv + 1536;             // 65,536
    short* Op   = (short*)(Cb + 65536);    // 8,388,608 shorts (two bf16 partials)
    float* Lb   = (float*)(Op + 8388608);  // 131,072 floats (two l partials)

    cvt_kernel<<<dim3(3201), dim3(256), 0, stream>>>(x, pos, Wq, Wk, Wv, Wpos, Wout, bq, bk, bv,
                                                     xb, posb, wqkv, wpb, wob, bqkv);
    gemm_qkv_pos<<<dim3(832), dim3(256), 0, stream>>>(xb, wqkv, bqkv, QKV, posb, wpb, Pm);
    kvprep_kernel<<<dim3(T_SEQ / 64, BATCH * NHEAD), dim3(256), 0, stream>>>(QKV, Pm, pbu, pbv, KP, Vt, Cb);
    attn_kernel<<<dim3(1024), dim3(256), 0, stream>>>(QKV, KP, Vt, Cb, Op, Lb);
    gemm_out_kernel<<<dim3(256), dim3(256), 0, stream>>>(Op, Lb, wob, bout, out);
}

// Round 8
// 218.529 us; speedup vs baseline: 1.3322x; 1.3322x over previous
//
#include <hip/hip_runtime.h>

typedef float f4 __attribute__((ext_vector_type(4)));
typedef __attribute__((ext_vector_type(8))) short bf16x8;
typedef __attribute__((ext_vector_type(4))) float f32x4;
typedef __attribute__((ext_vector_type(2))) int i32x2;
typedef __attribute__((ext_vector_type(4))) int i32x4;

#define T_SEQ 2048
#define NFEAT 512
#define NHEAD 8
#define DK    64
#define BATCH 4

using gptr_t = const __attribute__((address_space(1))) void*;
using lptr_t = __attribute__((address_space(3))) void*;

#define LOG2E_8 0.18033688011f   // 0.125 * log2(e)

// ---------------- failure ledger (do not retry without new evidence) -----------
// 1. v_cvt_pk_bf16_f32 inline asm for P-pack: FAILED correctness (absmax 0.227).
// 2. __launch_bounds__(512,8) 8-wave attn: VGPR cap 32 -> scratch spill,
//    WRITE_SIZE 24->149MB, attn 63.5->100.7us. Occupancy must come from LDS.
// 3. t-tile 64 attn (5 blocks/CU): staging-bound, attn 63.5->68.9us.
// 4. combine->gemm_out fusion: neutral. Kept (less traffic, fewer dispatches).
// 5. swapped-QK + kappa (Ps LDS deleted): neutral on time (65us) BUT halved
//    single-buffer LDS to 18.7KB -> enabler for dbuf at 4 blocks/CU.
// 6. barrier-free direct-from-L2 attn: 65->139us. MfmaUtil 11%, VALUBusy 17%:
//    per-fragment L2 gather (~200cy x 20 loads/iter/wave) cannot be hidden by
//    4 waves/SIMD. LDS staging is mandatory for MFMA operand feeds here.
// => this round: double-buffered KPs/Vts/cs ping-pong, ONE barrier per iter
//    (was two); ds_writes moved off the critical path into the compute phase.

static __device__ __forceinline__ short f2bf(float f) {
    unsigned u = __builtin_bit_cast(unsigned, f);
    u += 0x7fff + ((u >> 16) & 1);          // round-to-nearest-even
    return (short)(u >> 16);
}
static __device__ __forceinline__ float b2f(short s) {
    unsigned u = ((unsigned)(unsigned short)s) << 16;
    return __builtin_bit_cast(float, u);
}
// cheap-round pack (P values)
static __device__ __forceinline__ int pkbf(float a, float b) {
    unsigned ua = __builtin_bit_cast(unsigned, a) + 0x8000u;
    unsigned ub = __builtin_bit_cast(unsigned, b) + 0x8000u;
    return (int)((ua >> 16) | (ub & 0xFFFF0000u));
}
// RNE pack (epilogue O partials)
static __device__ __forceinline__ int pkbf_rne(float a, float b) {
    unsigned ua = __builtin_bit_cast(unsigned, a); ua += 0x7fff + ((ua >> 16) & 1);
    unsigned ub = __builtin_bit_cast(unsigned, b); ub += 0x7fff + ((ub >> 16) & 1);
    return (int)((ua >> 16) | (ub & 0xFFFF0000u));
}

// ---------------- fused fp32->bf16 conversion + weight/bias packing -------------
__global__ __launch_bounds__(256) void cvt_kernel(
    const float* __restrict__ x, const float* __restrict__ pos,
    const float* __restrict__ Wq, const float* __restrict__ Wk, const float* __restrict__ Wv,
    const float* __restrict__ Wpos, const float* __restrict__ Wout,
    const float* __restrict__ bq, const float* __restrict__ bk, const float* __restrict__ bv,
    short* __restrict__ xb, short* __restrict__ posb, short* __restrict__ wqkv,
    short* __restrict__ wpb, short* __restrict__ wob, float* __restrict__ bqkv)
{
    const int blk = blockIdx.x;
    const float* src; short* dst; int off;
    if      (blk < 2048) { src = x;    dst = xb;          off = blk * 2048; }
    else if (blk < 2560) { src = pos;  dst = posb;        off = (blk - 2048) * 2048; }
    else if (blk < 2688) { src = Wq;   dst = wqkv;        off = (blk - 2560) * 2048; }
    else if (blk < 2816) { src = Wk;   dst = wqkv + 262144; off = (blk - 2688) * 2048; }
    else if (blk < 2944) { src = Wv;   dst = wqkv + 524288; off = (blk - 2816) * 2048; }
    else if (blk < 3072) { src = Wpos; dst = wpb;         off = (blk - 2944) * 2048; }
    else if (blk < 3200) { src = Wout; dst = wob;         off = (blk - 3072) * 2048; }
    else {
        int t = threadIdx.x;
        bqkv[t]        = bq[t];        bqkv[256 + t]  = bq[256 + t];
        bqkv[512 + t]  = bk[t];        bqkv[768 + t]  = bk[256 + t];
        bqkv[1024 + t] = bv[t];        bqkv[1280 + t] = bv[256 + t];
        return;
    }
    int i = off + threadIdx.x * 8;
    f4 a = *(const f4*)(src + i);
    f4 b = *(const f4*)(src + i + 4);
    bf16x8 o;
#pragma unroll
    for (int j = 0; j < 4; ++j) { o[j] = f2bf(a[j]); o[4 + j] = f2bf(b[j]); }
    *(bf16x8*)(dst + i) = o;
}

// ---------------- bf16 MFMA GEMM tile: C[128,128] = A@B^T + bias ---------------
template<int OUT_BF16>
static __device__ __forceinline__ void gemm_tile(
    short* As, short* Bs,
    const short* __restrict__ A, const short* __restrict__ B,
    const float* __restrict__ bias, void* __restrict__ Cv,
    int N, int K, int row0, int col0)
{
    const int tid = threadIdx.x, lane = tid & 63, wave = tid >> 6;
    const int col = lane & 15, quad = lane >> 4;
    const int wm = (wave >> 1) * 64, wn = (wave & 1) * 64;
    const int rl = lane & 15;

    const short* Abase = A + (size_t)(row0 + wave * 32 + rl) * K + (lane >> 4) * 8;
    const short* Bbase = B + (size_t)(col0 + wave * 32 + rl) * K + (lane >> 4) * 8;

    f32x4 acc[4][4];
#pragma unroll
    for (int i = 0; i < 4; ++i)
#pragma unroll
        for (int j = 0; j < 4; ++j) acc[i][j] = (f32x4){0.f, 0.f, 0.f, 0.f};

    for (int k0 = 0; k0 < K; k0 += 64) {
        __syncthreads();
#pragma unroll
        for (int c = 0; c < 2; ++c)
#pragma unroll
            for (int hf = 0; hf < 2; ++hf) {
                __builtin_amdgcn_global_load_lds((gptr_t)(Abase + (size_t)(16 * c) * K + k0 + hf * 32),
                                                 (lptr_t)(As + wave * 2048 + c * 1024 + hf * 512), 16, 0, 0);
                __builtin_amdgcn_global_load_lds((gptr_t)(Bbase + (size_t)(16 * c) * K + k0 + hf * 32),
                                                 (lptr_t)(Bs + wave * 2048 + c * 1024 + hf * 512), 16, 0, 0);
            }
        __syncthreads();
#pragma unroll
        for (int kt = 0; kt < 2; ++kt) {
            bf16x8 af[4], bfr[4];
#pragma unroll
            for (int mt = 0; mt < 4; ++mt)
                af[mt] = *(const bf16x8*)&As[((wm >> 4) + mt) * 1024 + (kt * 4 + quad) * 128 + col * 8];
#pragma unroll
            for (int nt = 0; nt < 4; ++nt)
                bfr[nt] = *(const bf16x8*)&Bs[((wn >> 4) + nt) * 1024 + (kt * 4 + quad) * 128 + col * 8];
#pragma unroll
            for (int mt = 0; mt < 4; ++mt)
#pragma unroll
                for (int nt = 0; nt < 4; ++nt)
                    acc[mt][nt] = __builtin_amdgcn_mfma_f32_16x16x32_bf16(af[mt], bfr[nt], acc[mt][nt], 0, 0, 0);
        }
    }

    float bv4[4];
#pragma unroll
    for (int nt = 0; nt < 4; ++nt)
        bv4[nt] = bias ? bias[col0 + wn + nt * 16 + col] : 0.f;
#pragma unroll
    for (int mt = 0; mt < 4; ++mt)
#pragma unroll
        for (int reg = 0; reg < 4; ++reg) {
            int r = row0 + wm + mt * 16 + quad * 4 + reg;
#pragma unroll
            for (int nt = 0; nt < 4; ++nt) {
                int c = col0 + wn + nt * 16 + col;
                float v = acc[mt][nt][reg] + bv4[nt];
                if (OUT_BF16) ((short*)Cv)[(size_t)r * N + c] = f2bf(v);
                else          ((float*)Cv)[(size_t)r * N + c] = v;
            }
        }
}

// QKV (768 tiles, XCD-swizzled) + pos (64 tiles) in one dispatch
__global__ __launch_bounds__(256) void gemm_qkv_pos(
    const short* __restrict__ xb, const short* __restrict__ wqkv,
    const float* __restrict__ bqkv, short* __restrict__ QKV,
    const short* __restrict__ posb, const short* __restrict__ wpb,
    short* __restrict__ Pm)
{
    __shared__ short As[8192], Bs[8192];
    const int bid = blockIdx.x;
    if (bid < 768) {
        const int xcd = bid & 7, s = bid >> 3;
        const int row = xcd * 8 + (s & 7), colt = s >> 3;   // row 0..63, colt 0..11
        gemm_tile<1>(As, Bs, xb, wqkv, bqkv, QKV, 1536, 512, row * 128, colt * 128);
    } else {
        const int t = bid - 768;
        gemm_tile<1>(As, Bs, posb, wpb, nullptr, Pm, 512, 512, (t / 4) * 128, (t % 4) * 128);
    }
}

// ---------------- gemm_out with combine FUSED into A-staging -------------------
__global__ __launch_bounds__(256) void gemm_out_kernel(
    const short* __restrict__ Op, const float* __restrict__ Lb,
    const short* __restrict__ B, const float* __restrict__ bias,
    float* __restrict__ C)
{
    __shared__ short As[8192], Bs[8192];
    const int bid = blockIdx.x;
    const int xcd = bid & 7, s = bid >> 3;
    const int row0 = (xcd * 8 + (s & 7)) * 128, col0 = (s >> 3) * 128;
    const int N = 512, K = 512;

    const int tid = threadIdx.x, lane = tid & 63, wave = tid >> 6;
    const int col = lane & 15, quad = lane >> 4;
    const int wm = (wave >> 1) * 64, wn = (wave & 1) * 64;
    const int rl = lane & 15;

    const short* Bbase = B + (size_t)(col0 + wave * 32 + rl) * K + quad * 8;
    const int rA0 = row0 + wave * 32 + rl;   // c=0 staging row; c=1 is +16

    f32x4 acc[4][4];
#pragma unroll
    for (int i = 0; i < 4; ++i)
#pragma unroll
        for (int j = 0; j < 4; ++j) acc[i][j] = (f32x4){0.f, 0.f, 0.f, 0.f};

    for (int k0 = 0; k0 < K; k0 += 64) {
        const int h = k0 >> 6;
        __syncthreads();
        // B staging first (stays in flight under the A combine)
#pragma unroll
        for (int c = 0; c < 2; ++c)
#pragma unroll
            for (int hf = 0; hf < 2; ++hf)
                __builtin_amdgcn_global_load_lds((gptr_t)(Bbase + (size_t)(16 * c) * K + k0 + hf * 32),
                                                 (lptr_t)(Bs + wave * 2048 + c * 1024 + hf * 512), 16, 0, 0);
        // A staging: combine two unnormalized halves, normalize, ds_write
#pragma unroll
        for (int c = 0; c < 2; ++c) {
            const int r  = rA0 + c * 16;
            const int t  = r & 2047;
            const int bh = (r >> 11) * 8 + h;
            const float l = Lb[bh * T_SEQ + t] + Lb[65536 + bh * T_SEQ + t];
            const float inv = 1.f / l;
#pragma unroll
            for (int hf = 0; hf < 2; ++hf) {
                const short* src = Op + (size_t)r * NFEAT + k0 + hf * 32 + quad * 8;
                bf16x8 o1 = *(const bf16x8*)src;
                bf16x8 o2 = *(const bf16x8*)(src + 4194304);
                bf16x8 oc;
#pragma unroll
                for (int j = 0; j < 8; ++j) oc[j] = f2bf((b2f(o1[j]) + b2f(o2[j])) * inv);
                *(bf16x8*)&As[wave * 2048 + c * 1024 + hf * 512 + lane * 8] = oc;
            }
        }
        __syncthreads();
#pragma unroll
        for (int kt = 0; kt < 2; ++kt) {
            bf16x8 af[4], bfr[4];
#pragma unroll
            for (int mt = 0; mt < 4; ++mt)
                af[mt] = *(const bf16x8*)&As[((wm >> 4) + mt) * 1024 + (kt * 4 + quad) * 128 + col * 8];
#pragma unroll
            for (int nt = 0; nt < 4; ++nt)
                bfr[nt] = *(const bf16x8*)&Bs[((wn >> 4) + nt) * 1024 + (kt * 4 + quad) * 128 + col * 8];
#pragma unroll
            for (int mt = 0; mt < 4; ++mt)
#pragma unroll
                for (int nt = 0; nt < 4; ++nt)
                    acc[mt][nt] = __builtin_amdgcn_mfma_f32_16x16x32_bf16(af[mt], bfr[nt], acc[mt][nt], 0, 0, 0);
        }
    }

    float bv4[4];
#pragma unroll
    for (int nt = 0; nt < 4; ++nt)
        bv4[nt] = bias[col0 + wn + nt * 16 + col];
#pragma unroll
    for (int mt = 0; mt < 4; ++mt)
#pragma unroll
        for (int reg = 0; reg < 4; ++reg) {
            int r = row0 + wm + mt * 16 + quad * 4 + reg;
#pragma unroll
            for (int nt = 0; nt < 4; ++nt) {
                int c = col0 + wn + nt * 16 + col;
                C[(size_t)r * N + c] = acc[mt][nt][reg] + bv4[nt];
            }
        }
}

// ---------------- fused: KP = K+P, cb = (log2e/8)*(u.k+vb.p), Vt transpose -----
__global__ __launch_bounds__(256) void kvprep_kernel(
    const short* __restrict__ qkv, const short* __restrict__ pm,
    const float* __restrict__ u, const float* __restrict__ vb,
    short* __restrict__ kp, short* __restrict__ vt, float* __restrict__ cb)
{
    __shared__ short tile[64][72];
    const int tid = threadIdx.x, lr = tid >> 2, lc = (tid & 3) * 16;
    const int bh = blockIdx.y, b = bh >> 3, h = bh & 7, s0 = blockIdx.x * 64;

    const short* kptr = qkv + (size_t)(b * T_SEQ + s0 + lr) * 1536 + 512 + h * DK + lc;
    const short* pptr = pm + (size_t)(s0 + lr) * NFEAT + h * DK + lc;
    const short* vptr = qkv + (size_t)(b * T_SEQ + s0 + lr) * 1536 + 1024 + h * DK + lc;
    bf16x8 k0_ = *(const bf16x8*)kptr,       k1_ = *(const bf16x8*)(kptr + 8);
    bf16x8 p0_ = *(const bf16x8*)pptr,       p1_ = *(const bf16x8*)(pptr + 8);
    bf16x8 v0_ = *(const bf16x8*)vptr,       v1_ = *(const bf16x8*)(vptr + 8);

    float c = 0.f;
    bf16x8 o0, o1;
#pragma unroll
    for (int j = 0; j < 8; ++j) {
        float kf = b2f(k0_[j]), pf = b2f(p0_[j]);
        o0[j] = f2bf(kf + pf);
        c += u[h * DK + lc + j] * kf + vb[h * DK + lc + j] * pf;
        float kf1 = b2f(k1_[j]), pf1 = b2f(p1_[j]);
        o1[j] = f2bf(kf1 + pf1);
        c += u[h * DK + lc + 8 + j] * kf1 + vb[h * DK + lc + 8 + j] * pf1;
    }
    short* kpd = kp + ((size_t)bh * T_SEQ + s0 + lr) * DK + lc;
    *(bf16x8*)kpd       = o0;
    *(bf16x8*)(kpd + 8) = o1;
    c += __shfl_xor(c, 1);
    c += __shfl_xor(c, 2);
    if ((tid & 3) == 0) cb[(size_t)bh * T_SEQ + s0 + lr] = LOG2E_8 * c;

    *(bf16x8*)&tile[lr][lc]     = v0_;
    *(bf16x8*)&tile[lr][lc + 8] = v1_;
    __syncthreads();
    short* dst = vt + (size_t)(bh * DK + lr) * T_SEQ + s0 + lc;
    bf16x8 t0_, t1_;
#pragma unroll
    for (int j = 0; j < 8; ++j) { t0_[j] = tile[lc + j][lr]; t1_[j] = tile[lc + 8 + j][lr]; }
    *(bf16x8*)dst       = t0_;
    *(bf16x8*)(dst + 8) = t1_;
}

// ---------------- flash attention, swapped-QK, DOUBLE-BUFFERED staging ---------
// Grid 1024 (4 blocks/CU). Round-6 swapped-QK compute (proven) with KPs/Vts/cs
// ping-ponged: ds_writes target the idle buffer DURING the compute phase and
// only ONE __syncthreads per iteration remains (end-of-iter). Correctness:
// the barrier at iter end guarantees (a) buf[cur^1] fully written before any
// wave reads it at iter+1, (b) all reads of buf[cur] done before it is
// overwritten at iter+1. LDS 2x18.7KB = 37.4KB -> still 4 blocks/CU.
// Loads run 2 tiles ahead (last-iter overreads land in adjacent workspace
// buffers, values unused).
__global__ __launch_bounds__(256, 4) void attn_kernel(
    const short* __restrict__ qkv, const short* __restrict__ kp,
    const short* __restrict__ vt, const float* __restrict__ cb,
    short* __restrict__ Op, float* __restrict__ Lb)
{
    __shared__ __align__(16) short KPs[2][64][72], Vts[2][64][72];
    __shared__ float cs[2][64];
    const int tid = threadIdx.x, lane = tid & 63, wave = tid >> 6;   // 4 waves
    const int col = lane & 15, quad = lane >> 4;
    const int idx = blockIdx.x;
    const int xcd = idx & 7, slot = idx >> 3;        // slot 0..127
    const int half = slot & 1;
    const int t0 = ((slot >> 1) & 15) * 128;
    const int bh = (slot >> 5) * 8 + xcd;            // 4 bh per XCD -> 2MB KV in L2
    const int base = half * 1024;                    // key range [base, base+1024)
    const int b = bh >> 3, h = bh & 7;

    // Q fragments (MFMA B-operand)
    bf16x8 qa[2][2];
#pragma unroll
    for (int g = 0; g < 2; ++g) {
        const short* qb = qkv + (size_t)(b * T_SEQ + t0 + wave * 32 + g * 16 + col) * 1536 + h * DK + quad * 8;
        qa[g][0] = *(const bf16x8*)qb;
        qa[g][1] = *(const bf16x8*)(qb + 32);
    }

    // ones A-fragment (bf16 1.0) for the row-sum MFMA
    bf16x8 onesb;
#pragma unroll
    for (int j = 0; j < 8; ++j) onesb[j] = (short)0x3F80;

    const int lr  = tid >> 2;             // 0..63 staging row (slot index)
    const int lcq = (tid & 3) * 16;       // 0,16,32,48
    // kappa: slot -> actual key (bijective bit swap)
    const int kap  = (lr & 32) | ((lr & 12) << 1) | ((lr & 16) >> 2) | (lr & 3);
    const int kapt = (tid & 32) | ((tid & 12) << 1) | ((tid & 16) >> 2) | (tid & 3);

    const short* kpbase = kp + (size_t)bh * T_SEQ * DK;
    const short* vtbase = vt + (size_t)bh * DK * T_SEQ;

    // streaming prefetch pointers
    const short* kpp = kpbase + (size_t)(base + kap) * DK + lcq;
    const short* vtp = vtbase + (size_t)lr * T_SEQ + base + lcq;
    const float* cbp = cb + (size_t)bh * T_SEQ + base + kapt;

    // prologue: tile 0 -> regs -> buf0; tile 1 -> regs; one barrier
    bf16x8 kpr0 = *(const bf16x8*)kpp;
    bf16x8 kpr1 = *(const bf16x8*)(kpp + 8);
    bf16x8 vtr0 = *(const bf16x8*)vtp;
    bf16x8 vtr1 = *(const bf16x8*)(vtp + 8);
    float cbr = (tid < 64) ? *cbp : 0.f;

    *(bf16x8*)&KPs[0][lr][lcq]     = kpr0;
    *(bf16x8*)&KPs[0][lr][lcq + 8] = kpr1;
    *(bf16x8*)&Vts[0][lr][lcq]     = vtr0;
    *(bf16x8*)&Vts[0][lr][lcq + 8] = vtr1;
    if (tid < 64) cs[0][tid] = cbr;

    kpp += 64 * DK; vtp += 64; cbp += 64;
    kpr0 = *(const bf16x8*)kpp;
    kpr1 = *(const bf16x8*)(kpp + 8);
    vtr0 = *(const bf16x8*)vtp;
    vtr1 = *(const bf16x8*)(vtp + 8);
    if (tid < 64) cbr = *cbp;
    __syncthreads();

    f32x4 Oacc[2][4];   // O^T: [g][dt], lane: d = dt*16+quad*4+reg, qrow = col+16g
    f32x4 Lacc[2];
#pragma unroll
    for (int g = 0; g < 2; ++g) {
        Lacc[g] = (f32x4){0.f, 0.f, 0.f, 0.f};
#pragma unroll
        for (int i = 0; i < 4; ++i) Oacc[g][i] = (f32x4){0.f, 0.f, 0.f, 0.f};
    }

    for (int it = 0; it < 16; ++it) {
        const int cur = it & 1;
        // write tile it+1 (in regs) to the idle buffer -- overlaps compute below
        *(bf16x8*)&KPs[cur ^ 1][lr][lcq]     = kpr0;
        *(bf16x8*)&KPs[cur ^ 1][lr][lcq + 8] = kpr1;
        *(bf16x8*)&Vts[cur ^ 1][lr][lcq]     = vtr0;
        *(bf16x8*)&Vts[cur ^ 1][lr][lcq + 8] = vtr1;
        if (tid < 64) cs[cur ^ 1][tid] = cbr;

        // issue loads for tile it+2 (2-tile overread on final iters, unused)
        kpp += 64 * DK; vtp += 64; cbp += 64;
        kpr0 = *(const bf16x8*)kpp;
        kpr1 = *(const bf16x8*)(kpp + 8);
        vtr0 = *(const bf16x8*)vtp;
        vtr1 = *(const bf16x8*)(vtp + 8);
        if (tid < 64) cbr = *cbp;

        // QK swapped: S^T[slot][qrow]; KP fragments as A, Q fragments as B
        f32x4 S[2][4];
#pragma unroll
        for (int g = 0; g < 2; ++g)
#pragma unroll
            for (int nt = 0; nt < 4; ++nt) S[g][nt] = (f32x4){0.f, 0.f, 0.f, 0.f};
#pragma unroll
        for (int nt = 0; nt < 4; ++nt) {
            bf16x8 a0 = *(const bf16x8*)&KPs[cur][nt * 16 + col][quad * 8];
            bf16x8 a1 = *(const bf16x8*)&KPs[cur][nt * 16 + col][32 + quad * 8];
            S[0][nt] = __builtin_amdgcn_mfma_f32_16x16x32_bf16(a0, qa[0][0], S[0][nt], 0, 0, 0);
            S[1][nt] = __builtin_amdgcn_mfma_f32_16x16x32_bf16(a0, qa[1][0], S[1][nt], 0, 0, 0);
            S[0][nt] = __builtin_amdgcn_mfma_f32_16x16x32_bf16(a1, qa[0][1], S[0][nt], 0, 0, 0);
            S[1][nt] = __builtin_amdgcn_mfma_f32_16x16x32_bf16(a1, qa[1][1], S[1][nt], 0, 0, 0);
        }
        // softmax: exponent bias cs[cur][slot], slot = nt*16 + quad*4 + reg
        int pk_[2][4][2];
#pragma unroll
        for (int nt = 0; nt < 4; ++nt) {
            const f4 cvn = *(const f4*)&cs[cur][nt * 16 + quad * 4];
#pragma unroll
            for (int g = 0; g < 2; ++g) {
                float e0 = __builtin_amdgcn_exp2f(fmaf(S[g][nt][0], LOG2E_8, cvn[0]));
                float e1 = __builtin_amdgcn_exp2f(fmaf(S[g][nt][1], LOG2E_8, cvn[1]));
                float e2 = __builtin_amdgcn_exp2f(fmaf(S[g][nt][2], LOG2E_8, cvn[2]));
                float e3 = __builtin_amdgcn_exp2f(fmaf(S[g][nt][3], LOG2E_8, cvn[3]));
                pk_[g][nt][0] = pkbf(e0, e1);
                pk_[g][nt][1] = pkbf(e2, e3);
            }
        }
        // PV swapped: O^T += mfma(Vt-as-A, P-as-B); P fragment is lane-local.
#pragma unroll
        for (int kt = 0; kt < 2; ++kt) {
            i32x4 w0 = (i32x4){pk_[0][2 * kt][0], pk_[0][2 * kt][1], pk_[0][2 * kt + 1][0], pk_[0][2 * kt + 1][1]};
            i32x4 w1 = (i32x4){pk_[1][2 * kt][0], pk_[1][2 * kt][1], pk_[1][2 * kt + 1][0], pk_[1][2 * kt + 1][1]};
            bf16x8 pf0 = __builtin_bit_cast(bf16x8, w0);
            bf16x8 pf1 = __builtin_bit_cast(bf16x8, w1);
            Lacc[0] = __builtin_amdgcn_mfma_f32_16x16x32_bf16(onesb, pf0, Lacc[0], 0, 0, 0);
            Lacc[1] = __builtin_amdgcn_mfma_f32_16x16x32_bf16(onesb, pf1, Lacc[1], 0, 0, 0);
#pragma unroll
            for (int dt = 0; dt < 4; ++dt) {
                bf16x8 vb = *(const bf16x8*)&Vts[cur][dt * 16 + col][kt * 32 + quad * 8];
                Oacc[0][dt] = __builtin_amdgcn_mfma_f32_16x16x32_bf16(vb, pf0, Oacc[0][dt], 0, 0, 0);
                Oacc[1][dt] = __builtin_amdgcn_mfma_f32_16x16x32_bf16(vb, pf1, Oacc[1][dt], 0, 0, 0);
            }
        }
        __syncthreads();   // single barrier: buf[cur^1] ready; buf[cur] reusable
    }
    // epilogue: O^T lane layout -> packed 8B stores; l from any Lacc row
    short* ophalf = Op + (size_t)half * 4194304;
    float* lhalf  = Lb + (size_t)half * 65536 + (size_t)bh * T_SEQ;
#pragma unroll
    for (int g = 0; g < 2; ++g) {
        const int t = t0 + wave * 32 + g * 16 + col;
        if (quad == 0) lhalf[t] = Lacc[g][0];
        short* op = ophalf + (size_t)(b * T_SEQ + t) * NFEAT + h * DK;
#pragma unroll
        for (int dt = 0; dt < 4; ++dt) {
            i32x2 w;
            w[0] = pkbf_rne(Oacc[g][dt][0], Oacc[g][dt][1]);
            w[1] = pkbf_rne(Oacc[g][dt][2], Oacc[g][dt][3]);
            *(i32x2*)(op + dt * 16 + quad * 4) = w;
        }
    }
}

extern "C" void kernel_launch(void* const* d_in, const int* in_sizes, int n_in,
                              void* d_out, int out_size, void* d_ws, size_t ws_size,
                              hipStream_t stream)
{
    const float* x    = (const float*)d_in[0];
    const float* pos  = (const float*)d_in[1];
    const float* Wq   = (const float*)d_in[2];
    const float* bq   = (const float*)d_in[3];
    const float* Wk   = (const float*)d_in[4];
    const float* bk   = (const float*)d_in[5];
    const float* Wv   = (const float*)d_in[6];
    const float* bv   = (const float*)d_in[7];
    const float* Wpos = (const float*)d_in[8];
    const float* Wout = (const float*)d_in[9];
    const float* bout = (const float*)d_in[10];
    const float* pbu  = (const float*)d_in[11];
    const float* pbv  = (const float*)d_in[12];
    float* out = (float*)d_out;

    short* xb   = (short*)d_ws;            // 4,194,304
    short* posb = xb   + 4194304;          // 1,048,576
    short* wqkv = posb + 1048576;          //   786,432
    short* wpb  = wqkv + 786432;           //   262,144
    short* wob  = wpb  + 262144;           //   262,144
    short* QKV  = wob  + 262144;           // 12,582,912  [8192][1536] (Q|K|V)
    short* Pm   = QKV  + 12582912;         // 1,048,576   [2048][512]
    short* KP   = Pm   + 1048576;          // 4,194,304   [bh][s][64]
    short* Vt   = KP   + 4194304;          // 4,194,304   [bh][d][t]
    short* AttO = Vt   + 4194304;          // 4,194,304   (unused after fusion)
    float* bqkv = (float*)(AttO + 4194304);
    float* Cb   = bqkv + 1536;             // 65,536
    short* Op   = (short*)(Cb + 65536);    // 8,388,608 shorts (two bf16 partials)
    float* Lb   = (float*)(Op + 8388608);  // 131,072 floats (two l partials)

    cvt_kernel<<<dim3(3201), dim3(256), 0, stream>>>(x, pos, Wq, Wk, Wv, Wpos, Wout, bq, bk, bv,
                                                     xb, posb, wqkv, wpb, wob, bqkv);
    gemm_qkv_pos<<<dim3(832), dim3(256), 0, stream>>>(xb, wqkv, bqkv, QKV, posb, wpb, Pm);
    kvprep_kernel<<<dim3(T_SEQ / 64, BATCH * NHEAD), dim3(256), 0, stream>>>(QKV, Pm, pbu, pbv, KP, Vt, Cb);
    attn_kernel<<<dim3(1024), dim3(256), 0, stream>>>(QKV, KP, Vt, Cb, Op, Lb);
    gemm_out_kernel<<<dim3(256), dim3(256), 0, stream>>>(Op, Lb, wob, bout, out);
}

// Round 9
// 208.035 us; speedup vs baseline: 1.3993x; 1.0504x over previous
//
#include <hip/hip_runtime.h>

typedef float f4 __attribute__((ext_vector_type(4)));
typedef __attribute__((ext_vector_type(8))) short bf16x8;
typedef __attribute__((ext_vector_type(4))) float f32x4;
typedef __attribute__((ext_vector_type(2))) int i32x2;
typedef __attribute__((ext_vector_type(4))) int i32x4;

#define T_SEQ 2048
#define NFEAT 512
#define NHEAD 8
#define DK    64
#define BATCH 4

using gptr_t = const __attribute__((address_space(1))) void*;
using lptr_t = __attribute__((address_space(3))) void*;

#define LOG2E_8 0.18033688011f   // 0.125 * log2(e)

// ---------------- failure ledger (do not retry without new evidence) -----------
// 1. v_cvt_pk_bf16_f32 inline asm for P-pack: FAILED correctness (absmax 0.227).
// 2. __launch_bounds__(512,8) 8-wave attn: VGPR cap 32 -> scratch spill,
//    WRITE_SIZE 24->149MB, attn 63.5->100.7us. Occupancy must come from LDS.
// 3. t-tile 64 attn (5 blocks/CU): staging-bound, attn 63.5->68.9us.
// 4. combine->gemm_out fusion: neutral on time. Kept (less traffic/dispatches).
// 5. swapped-QK + kappa (Ps LDS deleted): neutral (65us); halved LDS to 18.7KB.
// 6. barrier-free direct-from-L2 attn: 65->139us. 4 waves/SIMD cannot hide
//    per-fragment L2 latency. LDS staging mandatory for MFMA feeds.
// 7. double-buffer + 1 barrier/iter: 65->68us (slightly worse). ATTN IS PINNED
//    at ~64-66us in this block shape; 7 structural levers all landed 63.5-68.
//    Keep round-6 single-buffer version; stop editing attn structure.
// => this round: (a) revert attn to round-6 + T5 setprio around MFMA clusters;
//    (b) gemm_out 256 blocks = 1 wave/SIMD (zero TLP, exposed L2 latency) ->
//    64x128 tiles, 512 blocks = 2 blocks/CU. Dtotal - Dattn isolates gemm_out.

static __device__ __forceinline__ short f2bf(float f) {
    unsigned u = __builtin_bit_cast(unsigned, f);
    u += 0x7fff + ((u >> 16) & 1);          // round-to-nearest-even
    return (short)(u >> 16);
}
static __device__ __forceinline__ float b2f(short s) {
    unsigned u = ((unsigned)(unsigned short)s) << 16;
    return __builtin_bit_cast(float, u);
}
// cheap-round pack (P values)
static __device__ __forceinline__ int pkbf(float a, float b) {
    unsigned ua = __builtin_bit_cast(unsigned, a) + 0x8000u;
    unsigned ub = __builtin_bit_cast(unsigned, b) + 0x8000u;
    return (int)((ua >> 16) | (ub & 0xFFFF0000u));
}
// RNE pack (epilogue O partials)
static __device__ __forceinline__ int pkbf_rne(float a, float b) {
    unsigned ua = __builtin_bit_cast(unsigned, a); ua += 0x7fff + ((ua >> 16) & 1);
    unsigned ub = __builtin_bit_cast(unsigned, b); ub += 0x7fff + ((ub >> 16) & 1);
    return (int)((ua >> 16) | (ub & 0xFFFF0000u));
}

// ---------------- fused fp32->bf16 conversion + weight/bias packing -------------
__global__ __launch_bounds__(256) void cvt_kernel(
    const float* __restrict__ x, const float* __restrict__ pos,
    const float* __restrict__ Wq, const float* __restrict__ Wk, const float* __restrict__ Wv,
    const float* __restrict__ Wpos, const float* __restrict__ Wout,
    const float* __restrict__ bq, const float* __restrict__ bk, const float* __restrict__ bv,
    short* __restrict__ xb, short* __restrict__ posb, short* __restrict__ wqkv,
    short* __restrict__ wpb, short* __restrict__ wob, float* __restrict__ bqkv)
{
    const int blk = blockIdx.x;
    const float* src; short* dst; int off;
    if      (blk < 2048) { src = x;    dst = xb;          off = blk * 2048; }
    else if (blk < 2560) { src = pos;  dst = posb;        off = (blk - 2048) * 2048; }
    else if (blk < 2688) { src = Wq;   dst = wqkv;        off = (blk - 2560) * 2048; }
    else if (blk < 2816) { src = Wk;   dst = wqkv + 262144; off = (blk - 2688) * 2048; }
    else if (blk < 2944) { src = Wv;   dst = wqkv + 524288; off = (blk - 2816) * 2048; }
    else if (blk < 3072) { src = Wpos; dst = wpb;         off = (blk - 2944) * 2048; }
    else if (blk < 3200) { src = Wout; dst = wob;         off = (blk - 3072) * 2048; }
    else {
        int t = threadIdx.x;
        bqkv[t]        = bq[t];        bqkv[256 + t]  = bq[256 + t];
        bqkv[512 + t]  = bk[t];        bqkv[768 + t]  = bk[256 + t];
        bqkv[1024 + t] = bv[t];        bqkv[1280 + t] = bv[256 + t];
        return;
    }
    int i = off + threadIdx.x * 8;
    f4 a = *(const f4*)(src + i);
    f4 b = *(const f4*)(src + i + 4);
    bf16x8 o;
#pragma unroll
    for (int j = 0; j < 4; ++j) { o[j] = f2bf(a[j]); o[4 + j] = f2bf(b[j]); }
    *(bf16x8*)(dst + i) = o;
}

// ---------------- bf16 MFMA GEMM tile: C[128,128] = A@B^T + bias ---------------
template<int OUT_BF16>
static __device__ __forceinline__ void gemm_tile(
    short* As, short* Bs,
    const short* __restrict__ A, const short* __restrict__ B,
    const float* __restrict__ bias, void* __restrict__ Cv,
    int N, int K, int row0, int col0)
{
    const int tid = threadIdx.x, lane = tid & 63, wave = tid >> 6;
    const int col = lane & 15, quad = lane >> 4;
    const int wm = (wave >> 1) * 64, wn = (wave & 1) * 64;
    const int rl = lane & 15;

    const short* Abase = A + (size_t)(row0 + wave * 32 + rl) * K + (lane >> 4) * 8;
    const short* Bbase = B + (size_t)(col0 + wave * 32 + rl) * K + (lane >> 4) * 8;

    f32x4 acc[4][4];
#pragma unroll
    for (int i = 0; i < 4; ++i)
#pragma unroll
        for (int j = 0; j < 4; ++j) acc[i][j] = (f32x4){0.f, 0.f, 0.f, 0.f};

    for (int k0 = 0; k0 < K; k0 += 64) {
        __syncthreads();
#pragma unroll
        for (int c = 0; c < 2; ++c)
#pragma unroll
            for (int hf = 0; hf < 2; ++hf) {
                __builtin_amdgcn_global_load_lds((gptr_t)(Abase + (size_t)(16 * c) * K + k0 + hf * 32),
                                                 (lptr_t)(As + wave * 2048 + c * 1024 + hf * 512), 16, 0, 0);
                __builtin_amdgcn_global_load_lds((gptr_t)(Bbase + (size_t)(16 * c) * K + k0 + hf * 32),
                                                 (lptr_t)(Bs + wave * 2048 + c * 1024 + hf * 512), 16, 0, 0);
            }
        __syncthreads();
#pragma unroll
        for (int kt = 0; kt < 2; ++kt) {
            bf16x8 af[4], bfr[4];
#pragma unroll
            for (int mt = 0; mt < 4; ++mt)
                af[mt] = *(const bf16x8*)&As[((wm >> 4) + mt) * 1024 + (kt * 4 + quad) * 128 + col * 8];
#pragma unroll
            for (int nt = 0; nt < 4; ++nt)
                bfr[nt] = *(const bf16x8*)&Bs[((wn >> 4) + nt) * 1024 + (kt * 4 + quad) * 128 + col * 8];
#pragma unroll
            for (int mt = 0; mt < 4; ++mt)
#pragma unroll
                for (int nt = 0; nt < 4; ++nt)
                    acc[mt][nt] = __builtin_amdgcn_mfma_f32_16x16x32_bf16(af[mt], bfr[nt], acc[mt][nt], 0, 0, 0);
        }
    }

    float bv4[4];
#pragma unroll
    for (int nt = 0; nt < 4; ++nt)
        bv4[nt] = bias ? bias[col0 + wn + nt * 16 + col] : 0.f;
#pragma unroll
    for (int mt = 0; mt < 4; ++mt)
#pragma unroll
        for (int reg = 0; reg < 4; ++reg) {
            int r = row0 + wm + mt * 16 + quad * 4 + reg;
#pragma unroll
            for (int nt = 0; nt < 4; ++nt) {
                int c = col0 + wn + nt * 16 + col;
                float v = acc[mt][nt][reg] + bv4[nt];
                if (OUT_BF16) ((short*)Cv)[(size_t)r * N + c] = f2bf(v);
                else          ((float*)Cv)[(size_t)r * N + c] = v;
            }
        }
}

// QKV (768 tiles, XCD-swizzled) + pos (64 tiles) in one dispatch
__global__ __launch_bounds__(256) void gemm_qkv_pos(
    const short* __restrict__ xb, const short* __restrict__ wqkv,
    const float* __restrict__ bqkv, short* __restrict__ QKV,
    const short* __restrict__ posb, const short* __restrict__ wpb,
    short* __restrict__ Pm)
{
    __shared__ short As[8192], Bs[8192];
    const int bid = blockIdx.x;
    if (bid < 768) {
        const int xcd = bid & 7, s = bid >> 3;
        const int row = xcd * 8 + (s & 7), colt = s >> 3;   // row 0..63, colt 0..11
        gemm_tile<1>(As, Bs, xb, wqkv, bqkv, QKV, 1536, 512, row * 128, colt * 128);
    } else {
        const int t = bid - 768;
        gemm_tile<1>(As, Bs, posb, wpb, nullptr, Pm, 512, 512, (t / 4) * 128, (t % 4) * 128);
    }
}

// ---------------- gemm_out, 64x128 tiles (512 blocks = 2 blocks/CU) -----------
// combine fused into A-staging as before; M-split only (B re-reads are cheap:
// wob = 0.5MB L2-resident; A re-read factor unchanged at 4). Wave layout 2x2:
// wm in {0,32}, wn in {0,64}; A-group = wave (wave stages rows wave*16..+15).
__global__ __launch_bounds__(256) void gemm_out_kernel(
    const short* __restrict__ Op, const float* __restrict__ Lb,
    const short* __restrict__ B, const float* __restrict__ bias,
    float* __restrict__ C)
{
    __shared__ short As[4096], Bs[8192];
    const int bid = blockIdx.x;
    const int xcd = bid & 7, s = bid >> 3;            // s 0..63
    const int row0 = (xcd * 16 + (s & 15)) * 64;      // 128 row-tiles of 64
    const int col0 = (s >> 4) * 128;                  // 4 col-tiles of 128
    const int N = 512, K = 512;

    const int tid = threadIdx.x, lane = tid & 63, wave = tid >> 6;
    const int col = lane & 15, quad = lane >> 4;
    const int wm = (wave >> 1) * 32, wn = (wave & 1) * 64;
    const int rl = lane & 15;

    const short* Bbase = B + (size_t)(col0 + wave * 32 + rl) * K + quad * 8;
    const int rA = row0 + wave * 16 + rl;             // this thread's staging row

    f32x4 acc[2][4];
#pragma unroll
    for (int i = 0; i < 2; ++i)
#pragma unroll
        for (int j = 0; j < 4; ++j) acc[i][j] = (f32x4){0.f, 0.f, 0.f, 0.f};

    for (int k0 = 0; k0 < K; k0 += 64) {
        const int h = k0 >> 6;
        __syncthreads();
        // B staging first (async, stays in flight under the A combine)
#pragma unroll
        for (int c = 0; c < 2; ++c)
#pragma unroll
            for (int hf = 0; hf < 2; ++hf)
                __builtin_amdgcn_global_load_lds((gptr_t)(Bbase + (size_t)(16 * c) * K + k0 + hf * 32),
                                                 (lptr_t)(Bs + wave * 2048 + c * 1024 + hf * 512), 16, 0, 0);
        // A staging: combine two unnormalized halves, normalize, ds_write
        {
            const int t  = rA & 2047;
            const int bh = (rA >> 11) * 8 + h;
            const float l = Lb[bh * T_SEQ + t] + Lb[65536 + bh * T_SEQ + t];
            const float inv = 1.f / l;
#pragma unroll
            for (int hf = 0; hf < 2; ++hf) {
                const short* src = Op + (size_t)rA * NFEAT + k0 + hf * 32 + quad * 8;
                bf16x8 o1 = *(const bf16x8*)src;
                bf16x8 o2 = *(const bf16x8*)(src + 4194304);
                bf16x8 oc;
#pragma unroll
                for (int j = 0; j < 8; ++j) oc[j] = f2bf((b2f(o1[j]) + b2f(o2[j])) * inv);
                *(bf16x8*)&As[wave * 1024 + hf * 512 + lane * 8] = oc;
            }
        }
        __syncthreads();
#pragma unroll
        for (int kt = 0; kt < 2; ++kt) {
            bf16x8 af[2], bfr[4];
#pragma unroll
            for (int mt = 0; mt < 2; ++mt)
                af[mt] = *(const bf16x8*)&As[((wm >> 4) + mt) * 1024 + (kt * 4 + quad) * 128 + col * 8];
#pragma unroll
            for (int nt = 0; nt < 4; ++nt)
                bfr[nt] = *(const bf16x8*)&Bs[((wn >> 4) + nt) * 1024 + (kt * 4 + quad) * 128 + col * 8];
#pragma unroll
            for (int mt = 0; mt < 2; ++mt)
#pragma unroll
                for (int nt = 0; nt < 4; ++nt)
                    acc[mt][nt] = __builtin_amdgcn_mfma_f32_16x16x32_bf16(af[mt], bfr[nt], acc[mt][nt], 0, 0, 0);
        }
    }

    float bv4[4];
#pragma unroll
    for (int nt = 0; nt < 4; ++nt)
        bv4[nt] = bias[col0 + wn + nt * 16 + col];
#pragma unroll
    for (int mt = 0; mt < 2; ++mt)
#pragma unroll
        for (int reg = 0; reg < 4; ++reg) {
            int r = row0 + wm + mt * 16 + quad * 4 + reg;
#pragma unroll
            for (int nt = 0; nt < 4; ++nt) {
                int c = col0 + wn + nt * 16 + col;
                C[(size_t)r * N + c] = acc[mt][nt][reg] + bv4[nt];
            }
        }
}

// ---------------- fused: KP = K+P, cb = (log2e/8)*(u.k+vb.p), Vt transpose -----
__global__ __launch_bounds__(256) void kvprep_kernel(
    const short* __restrict__ qkv, const short* __restrict__ pm,
    const float* __restrict__ u, const float* __restrict__ vb,
    short* __restrict__ kp, short* __restrict__ vt, float* __restrict__ cb)
{
    __shared__ short tile[64][72];
    const int tid = threadIdx.x, lr = tid >> 2, lc = (tid & 3) * 16;
    const int bh = blockIdx.y, b = bh >> 3, h = bh & 7, s0 = blockIdx.x * 64;

    const short* kptr = qkv + (size_t)(b * T_SEQ + s0 + lr) * 1536 + 512 + h * DK + lc;
    const short* pptr = pm + (size_t)(s0 + lr) * NFEAT + h * DK + lc;
    const short* vptr = qkv + (size_t)(b * T_SEQ + s0 + lr) * 1536 + 1024 + h * DK + lc;
    bf16x8 k0_ = *(const bf16x8*)kptr,       k1_ = *(const bf16x8*)(kptr + 8);
    bf16x8 p0_ = *(const bf16x8*)pptr,       p1_ = *(const bf16x8*)(pptr + 8);
    bf16x8 v0_ = *(const bf16x8*)vptr,       v1_ = *(const bf16x8*)(vptr + 8);

    float c = 0.f;
    bf16x8 o0, o1;
#pragma unroll
    for (int j = 0; j < 8; ++j) {
        float kf = b2f(k0_[j]), pf = b2f(p0_[j]);
        o0[j] = f2bf(kf + pf);
        c += u[h * DK + lc + j] * kf + vb[h * DK + lc + j] * pf;
        float kf1 = b2f(k1_[j]), pf1 = b2f(p1_[j]);
        o1[j] = f2bf(kf1 + pf1);
        c += u[h * DK + lc + 8 + j] * kf1 + vb[h * DK + lc + 8 + j] * pf1;
    }
    short* kpd = kp + ((size_t)bh * T_SEQ + s0 + lr) * DK + lc;
    *(bf16x8*)kpd       = o0;
    *(bf16x8*)(kpd + 8) = o1;
    c += __shfl_xor(c, 1);
    c += __shfl_xor(c, 2);
    if ((tid & 3) == 0) cb[(size_t)bh * T_SEQ + s0 + lr] = LOG2E_8 * c;

    *(bf16x8*)&tile[lr][lc]     = v0_;
    *(bf16x8*)&tile[lr][lc + 8] = v1_;
    __syncthreads();
    short* dst = vt + (size_t)(bh * DK + lr) * T_SEQ + s0 + lc;
    bf16x8 t0_, t1_;
#pragma unroll
    for (int j = 0; j < 8; ++j) { t0_[j] = tile[lc + j][lr]; t1_[j] = tile[lc + 8 + j][lr]; }
    *(bf16x8*)dst       = t0_;
    *(bf16x8*)(dst + 8) = t1_;
}

// ---------------- flash attention, swapped-QK (round-6 proven) + setprio -------
// Grid 1024 (4 blocks/CU). Single-buffer staging, 2 barriers/iter — measured
// equal-best (65us) across 7 structural variants; see ledger. T5 setprio wraps
// the MFMA clusters: 4 independent blocks/CU put waves of a SIMD at different
// phases, so priority arbitration can favor MFMA-entering waves (m191 regime).
__global__ __launch_bounds__(256, 4) void attn_kernel(
    const short* __restrict__ qkv, const short* __restrict__ kp,
    const short* __restrict__ vt, const float* __restrict__ cb,
    short* __restrict__ Op, float* __restrict__ Lb)
{
    __shared__ __align__(16) short KPs[64][72], Vts[64][72];
    __shared__ float cs[64];
    const int tid = threadIdx.x, lane = tid & 63, wave = tid >> 6;   // 4 waves
    const int col = lane & 15, quad = lane >> 4;
    const int idx = blockIdx.x;
    const int xcd = idx & 7, slot = idx >> 3;        // slot 0..127
    const int half = slot & 1;
    const int t0 = ((slot >> 1) & 15) * 128;
    const int bh = (slot >> 5) * 8 + xcd;            // 4 bh per XCD -> 2MB KV in L2
    const int base = half * 1024;                    // key range [base, base+1024)
    const int b = bh >> 3, h = bh & 7;

    // Q fragments (MFMA B-operand)
    bf16x8 qa[2][2];
#pragma unroll
    for (int g = 0; g < 2; ++g) {
        const short* qb = qkv + (size_t)(b * T_SEQ + t0 + wave * 32 + g * 16 + col) * 1536 + h * DK + quad * 8;
        qa[g][0] = *(const bf16x8*)qb;
        qa[g][1] = *(const bf16x8*)(qb + 32);
    }

    // ones A-fragment (bf16 1.0) for the row-sum MFMA
    bf16x8 onesb;
#pragma unroll
    for (int j = 0; j < 8; ++j) onesb[j] = (short)0x3F80;

    const int lr  = tid >> 2;             // 0..63 staging row (slot index)
    const int lcq = (tid & 3) * 16;       // 0,16,32,48
    // kappa: slot -> actual key (bijective bit swap)
    const int kap  = (lr & 32) | ((lr & 12) << 1) | ((lr & 16) >> 2) | (lr & 3);
    const int kapt = (tid & 32) | ((tid & 12) << 1) | ((tid & 16) >> 2) | (tid & 3);

    const short* kpbase = kp + (size_t)bh * T_SEQ * DK;
    const short* vtbase = vt + (size_t)bh * DK * T_SEQ;

    // streaming prefetch pointers (advance by one 64-key tile per iter)
    const short* kpp = kpbase + (size_t)(base + kap) * DK + lcq;
    const short* vtp = vtbase + (size_t)lr * T_SEQ + base + lcq;
    const float* cbp = cb + (size_t)bh * T_SEQ + base + kapt;

    // prime the register pipeline (first tile of this half)
    bf16x8 kpr0 = *(const bf16x8*)kpp;
    bf16x8 kpr1 = *(const bf16x8*)(kpp + 8);
    bf16x8 vtr0 = *(const bf16x8*)vtp;
    bf16x8 vtr1 = *(const bf16x8*)(vtp + 8);
    float cbr = (tid < 64) ? *cbp : 0.f;

    f32x4 Oacc[2][4];   // O^T: [g][dt], lane: d = dt*16+quad*4+reg, qrow = col+16g
    f32x4 Lacc[2];
#pragma unroll
    for (int g = 0; g < 2; ++g) {
        Lacc[g] = (f32x4){0.f, 0.f, 0.f, 0.f};
#pragma unroll
        for (int i = 0; i < 4; ++i) Oacc[g][i] = (f32x4){0.f, 0.f, 0.f, 0.f};
    }

    for (int it = 0; it < 16; ++it) {
        __syncthreads();                 // prev iter's KPs/Vts reads done
        *(bf16x8*)&KPs[lr][lcq]     = kpr0;
        *(bf16x8*)&KPs[lr][lcq + 8] = kpr1;
        *(bf16x8*)&Vts[lr][lcq]     = vtr0;
        *(bf16x8*)&Vts[lr][lcq + 8] = vtr1;
        if (tid < 64) cs[tid] = cbr;
        __syncthreads();

        // prefetch next tile (pointer bump; last iter overreads into adjacent
        // workspace buffers, values unused)
        kpp += 64 * DK; vtp += 64; cbp += 64;
        kpr0 = *(const bf16x8*)kpp;
        kpr1 = *(const bf16x8*)(kpp + 8);
        vtr0 = *(const bf16x8*)vtp;
        vtr1 = *(const bf16x8*)(vtp + 8);
        if (tid < 64) cbr = *cbp;

        // QK swapped: S^T[slot][qrow]; KP fragments as A, Q fragments as B
        f32x4 S[2][4];
#pragma unroll
        for (int g = 0; g < 2; ++g)
#pragma unroll
            for (int nt = 0; nt < 4; ++nt) S[g][nt] = (f32x4){0.f, 0.f, 0.f, 0.f};
        __builtin_amdgcn_s_setprio(1);
#pragma unroll
        for (int nt = 0; nt < 4; ++nt) {
            bf16x8 a0 = *(const bf16x8*)&KPs[nt * 16 + col][quad * 8];
            bf16x8 a1 = *(const bf16x8*)&KPs[nt * 16 + col][32 + quad * 8];
            S[0][nt] = __builtin_amdgcn_mfma_f32_16x16x32_bf16(a0, qa[0][0], S[0][nt], 0, 0, 0);
            S[1][nt] = __builtin_amdgcn_mfma_f32_16x16x32_bf16(a0, qa[1][0], S[1][nt], 0, 0, 0);
            S[0][nt] = __builtin_amdgcn_mfma_f32_16x16x32_bf16(a1, qa[0][1], S[0][nt], 0, 0, 0);
            S[1][nt] = __builtin_amdgcn_mfma_f32_16x16x32_bf16(a1, qa[1][1], S[1][nt], 0, 0, 0);
        }
        __builtin_amdgcn_s_setprio(0);
        // softmax: exponent bias cs[slot], slot = nt*16 + quad*4 + reg
        int pk_[2][4][2];
#pragma unroll
        for (int nt = 0; nt < 4; ++nt) {
            const f4 cvn = *(const f4*)&cs[nt * 16 + quad * 4];
#pragma unroll
            for (int g = 0; g < 2; ++g) {
                float e0 = __builtin_amdgcn_exp2f(fmaf(S[g][nt][0], LOG2E_8, cvn[0]));
                float e1 = __builtin_amdgcn_exp2f(fmaf(S[g][nt][1], LOG2E_8, cvn[1]));
                float e2 = __builtin_amdgcn_exp2f(fmaf(S[g][nt][2], LOG2E_8, cvn[2]));
                float e3 = __builtin_amdgcn_exp2f(fmaf(S[g][nt][3], LOG2E_8, cvn[3]));
                pk_[g][nt][0] = pkbf(e0, e1);
                pk_[g][nt][1] = pkbf(e2, e3);
            }
        }
        // PV swapped: O^T += mfma(Vt-as-A, P-as-B); P fragment is lane-local.
        __builtin_amdgcn_s_setprio(1);
#pragma unroll
        for (int kt = 0; kt < 2; ++kt) {
            i32x4 w0 = (i32x4){pk_[0][2 * kt][0], pk_[0][2 * kt][1], pk_[0][2 * kt + 1][0], pk_[0][2 * kt + 1][1]};
            i32x4 w1 = (i32x4){pk_[1][2 * kt][0], pk_[1][2 * kt][1], pk_[1][2 * kt + 1][0], pk_[1][2 * kt + 1][1]};
            bf16x8 pf0 = __builtin_bit_cast(bf16x8, w0);
            bf16x8 pf1 = __builtin_bit_cast(bf16x8, w1);
            Lacc[0] = __builtin_amdgcn_mfma_f32_16x16x32_bf16(onesb, pf0, Lacc[0], 0, 0, 0);
            Lacc[1] = __builtin_amdgcn_mfma_f32_16x16x32_bf16(onesb, pf1, Lacc[1], 0, 0, 0);
#pragma unroll
            for (int dt = 0; dt < 4; ++dt) {
                bf16x8 vb = *(const bf16x8*)&Vts[dt * 16 + col][kt * 32 + quad * 8];
                Oacc[0][dt] = __builtin_amdgcn_mfma_f32_16x16x32_bf16(vb, pf0, Oacc[0][dt], 0, 0, 0);
                Oacc[1][dt] = __builtin_amdgcn_mfma_f32_16x16x32_bf16(vb, pf1, Oacc[1][dt], 0, 0, 0);
            }
        }
        __builtin_amdgcn_s_setprio(0);
    }
    // epilogue: O^T lane layout -> packed 8B stores; l from any Lacc row
    short* ophalf = Op + (size_t)half * 4194304;
    float* lhalf  = Lb + (size_t)half * 65536 + (size_t)bh * T_SEQ;
#pragma unroll
    for (int g = 0; g < 2; ++g) {
        const int t = t0 + wave * 32 + g * 16 + col;
        if (quad == 0) lhalf[t] = Lacc[g][0];
        short* op = ophalf + (size_t)(b * T_SEQ + t) * NFEAT + h * DK;
#pragma unroll
        for (int dt = 0; dt < 4; ++dt) {
            i32x2 w;
            w[0] = pkbf_rne(Oacc[g][dt][0], Oacc[g][dt][1]);
            w[1] = pkbf_rne(Oacc[g][dt][2], Oacc[g][dt][3]);
            *(i32x2*)(op + dt * 16 + quad * 4) = w;
        }
    }
}

extern "C" void kernel_launch(void* const* d_in, const int* in_sizes, int n_in,
                              void* d_out, int out_size, void* d_ws, size_t ws_size,
                              hipStream_t stream)
{
    const float* x    = (const float*)d_in[0];
    const float* pos  = (const float*)d_in[1];
    const float* Wq   = (const float*)d_in[2];
    const float* bq   = (const float*)d_in[3];
    const float* Wk   = (const float*)d_in[4];
    const float* bk   = (const float*)d_in[5];
    const float* Wv   = (const float*)d_in[6];
    const float* bv   = (const float*)d_in[7];
    const float* Wpos = (const float*)d_in[8];
    const float* Wout = (const float*)d_in[9];
    const float* bout = (const float*)d_in[10];
    const float* pbu  = (const float*)d_in[11];
    const float* pbv  = (const float*)d_in[12];
    float* out = (float*)d_out;

    short* xb   = (short*)d_ws;            // 4,194,304
    short* posb = xb   + 4194304;          // 1,048,576
    short* wqkv = posb + 1048576;          //   786,432
    short* wpb  = wqkv + 786432;           //   262,144
    short* wob  = wpb  + 262144;           //   262,144
    short* QKV  = wob  + 262144;           // 12,582,912  [8192][1536] (Q|K|V)
    short* Pm   = QKV  + 12582912;         // 1,048,576   [2048][512]
    short* KP   = Pm   + 1048576;          // 4,194,304   [bh][s][64]
    short* Vt   = KP   + 4194304;          // 4,194,304   [bh][d][t]
    short* AttO = Vt   + 4194304;          // 4,194,304   (unused after fusion)
    float* bqkv = (float*)(AttO + 4194304);
    float* Cb   = bqkv + 1536;             // 65,536
    short* Op   = (short*)(Cb + 65536);    // 8,388,608 shorts (two bf16 partials)
    float* Lb   = (float*)(Op + 8388608);  // 131,072 floats (two l partials)

    cvt_kernel<<<dim3(3201), dim3(256), 0, stream>>>(x, pos, Wq, Wk, Wv, Wpos, Wout, bq, bk, bv,
                                                     xb, posb, wqkv, wpb, wob, bqkv);
    gemm_qkv_pos<<<dim3(832), dim3(256), 0, stream>>>(xb, wqkv, bqkv, QKV, posb, wpb, Pm);
    kvprep_kernel<<<dim3(T_SEQ / 64, BATCH * NHEAD), dim3(256), 0, stream>>>(QKV, Pm, pbu, pbv, KP, Vt, Cb);
    attn_kernel<<<dim3(1024), dim3(256), 0, stream>>>(QKV, KP, Vt, Cb, Op, Lb);
    gemm_out_kernel<<<dim3(512), dim3(256), 0, stream>>>(Op, Lb, wob, bout, out);
}